// Round 1
// baseline (2139.863 us; speedup 1.0000x reference)
//
#include <hip/hip_runtime.h>
#include <math.h>

#define BB 2
#define TT 2048
#define DD 1024
#define NTHREADS 256
#define NWAVES 4

__device__ __forceinline__ float gelu_exact(float t) {
    return 0.5f * t * (1.0f + erff(t * 0.70710678118654752f));
}

__global__ __launch_bounds__(NTHREADS) void round_kernel(
    const float* __restrict__ h_in,
    float* __restrict__ h_out,
    const float* __restrict__ gain,        // already offset to round r (D floats)
    const float* __restrict__ bias,        // already offset to round r (D floats)
    const float* __restrict__ log_mix_r,   // scalar for this round
    const float* __restrict__ log_momentum,
    int K)
{
    __shared__ float s_scores[TT];
    __shared__ float s_hi[DD];
    __shared__ float s_wval[NWAVES];
    __shared__ int   s_widx[NWAVES];
    __shared__ int   s_sel[16];

    const int row  = blockIdx.x;          // 0 .. BB*TT-1
    const int b    = row / TT;
    const int i    = row % TT;
    const int tid  = threadIdx.x;
    const int lane = tid & 63;
    const int wave = tid >> 6;

    const float* hbase = h_in + (size_t)b * TT * DD;

    // stage h_i into LDS (float4)
    const float4* hi_g  = (const float4*)(hbase + (size_t)i * DD);
    float4*       s_hi4 = (float4*)s_hi;
    for (int t = tid; t < DD / 4; t += NTHREADS) s_hi4[t] = hi_g[t];
    __syncthreads();

    // ---- scores[j] = dot(h_i, h_j) for j in [0, i] ----
    for (int j = wave; j <= i; j += NWAVES) {
        const float4* hj = (const float4*)(hbase + (size_t)j * DD);
        float acc = 0.0f;
        #pragma unroll
        for (int t = 0; t < 4; ++t) {
            float4 a = s_hi4[lane + 64 * t];
            float4 v = hj[lane + 64 * t];
            acc += a.x * v.x + a.y * v.y + a.z * v.z + a.w * v.w;
        }
        #pragma unroll
        for (int off = 32; off >= 1; off >>= 1)
            acc += __shfl_down(acc, off, 64);
        if (lane == 0) s_scores[j] = acc;
    }
    __syncthreads();

    // ---- top-count selection (iterative block argmax) ----
    const int count = (i + 1 < K) ? (i + 1) : K;
    for (int k = 0; k < count; ++k) {
        float best = -INFINITY;
        int   bidx = -1;
        for (int j = tid; j <= i; j += NTHREADS) {
            float v = s_scores[j];
            if (v > best) { best = v; bidx = j; }
        }
        #pragma unroll
        for (int off = 32; off >= 1; off >>= 1) {
            float ov = __shfl_down(best, off, 64);
            int   oi = __shfl_down(bidx, off, 64);
            if (ov > best || (ov == best && oi != -1 && (bidx == -1 || oi < bidx))) {
                best = ov; bidx = oi;
            }
        }
        if (lane == 0) { s_wval[wave] = best; s_widx[wave] = bidx; }
        __syncthreads();
        if (tid == 0) {
            float bb = s_wval[0]; int bi = s_widx[0];
            for (int w = 1; w < NWAVES; ++w) {
                float wv = s_wval[w]; int wi = s_widx[w];
                if (wv > bb || (wv == bb && wi != -1 && (bi == -1 || wi < bi))) {
                    bb = wv; bi = wi;
                }
            }
            s_sel[k] = bi;
            s_scores[bi] = -INFINITY;   // remove for next iteration
        }
        __syncthreads();
    }

    // ---- aggregate mean of selected neighbors; pointwise epilogue ----
    const float mix      = 1.0f / (1.0f + expf(-log_mix_r[0]));
    const float momentum = 1.0f / (1.0f + expf(-log_momentum[0]));
    const float inv_cnt  = 1.0f / (float)count;

    // thread tid owns dims [4*tid, 4*tid+3]; D/4 == NTHREADS exactly
    float4 msg = make_float4(0.f, 0.f, 0.f, 0.f);
    for (int k = 0; k < count; ++k) {
        const float4* hs = (const float4*)(hbase + (size_t)s_sel[k] * DD);
        float4 v = hs[tid];
        msg.x += v.x; msg.y += v.y; msg.z += v.z; msg.w += v.w;
    }

    const float4 hi = s_hi4[tid];
    const float4 g4 = ((const float4*)gain)[tid];
    const float4 c4 = ((const float4*)bias)[tid];

    float4 o;
    {
        float m, t;
        m = msg.x * inv_cnt; t = (mix * hi.x + (1.f - mix) * m) * g4.x + c4.x;
        o.x = momentum * hi.x + (1.f - momentum) * gelu_exact(t);
        m = msg.y * inv_cnt; t = (mix * hi.y + (1.f - mix) * m) * g4.y + c4.y;
        o.y = momentum * hi.y + (1.f - momentum) * gelu_exact(t);
        m = msg.z * inv_cnt; t = (mix * hi.z + (1.f - mix) * m) * g4.z + c4.z;
        o.z = momentum * hi.z + (1.f - momentum) * gelu_exact(t);
        m = msg.w * inv_cnt; t = (mix * hi.w + (1.f - mix) * m) * g4.w + c4.w;
        o.w = momentum * hi.w + (1.f - momentum) * gelu_exact(t);
    }
    ((float4*)(h_out + (size_t)row * DD))[tid] = o;
}

__global__ __launch_bounds__(NTHREADS) void finalize_kernel(
    const float* __restrict__ h,
    const float* __restrict__ x,
    float* __restrict__ out,
    const float* __restrict__ log_scale)
{
    const int idx = blockIdx.x * NTHREADS + threadIdx.x;
    const float ls = log_scale[0];
    const float scale = log1pf(expf(ls)) + 0.01f;
    float4 hv = ((const float4*)h)[idx];
    float4 xv = ((const float4*)x)[idx];
    float4 o;
    o.x = (hv.x - xv.x) * scale;
    o.y = (hv.y - xv.y) * scale;
    o.z = (hv.z - xv.z) * scale;
    o.w = (hv.w - xv.w) * scale;
    ((float4*)out)[idx] = o;
}

extern "C" void kernel_launch(void* const* d_in, const int* in_sizes, int n_in,
                              void* d_out, int out_size, void* d_ws, size_t ws_size,
                              hipStream_t stream) {
    const float* x            = (const float*)d_in[0];
    const float* gain         = (const float*)d_in[1];
    const float* bias         = (const float*)d_in[2];
    const float* log_mix      = (const float*)d_in[3];
    const float* log_momentum = (const float*)d_in[4];
    const float* log_scale    = (const float*)d_in[5];
    float* out = (float*)d_out;

    float* h_ws = (float*)d_ws;              // 16 MB intermediate
    // round 0: x -> ws ; round 1: ws -> out(buf) ; round 2: out(buf) -> ws ;
    // finalize: (ws, x) -> out
    const int Ks[3] = {4, 8, 16};

    round_kernel<<<BB * TT, NTHREADS, 0, stream>>>(
        x, h_ws, gain + 0 * DD, bias + 0 * DD, log_mix + 0, log_momentum, Ks[0]);
    round_kernel<<<BB * TT, NTHREADS, 0, stream>>>(
        h_ws, out, gain + 1 * DD, bias + 1 * DD, log_mix + 1, log_momentum, Ks[1]);
    round_kernel<<<BB * TT, NTHREADS, 0, stream>>>(
        out, h_ws, gain + 2 * DD, bias + 2 * DD, log_mix + 2, log_momentum, Ks[2]);

    const int n4 = BB * TT * DD / 4;
    finalize_kernel<<<n4 / NTHREADS, NTHREADS, 0, stream>>>(h_ws, x, out, log_scale);
}

// Round 2
// 870.099 us; speedup vs baseline: 2.4593x; 2.4593x over previous
//
#include <hip/hip_runtime.h>
#include <math.h>

#define BB 2
#define TT 2048
#define DD 1024
#define NTHREADS 256

#define RTILE 64
#define CTILE 128
#define DCHUNK 32
#define NIT (TT / RTILE)    // 32
#define NJC (TT / CTILE)    // 16
#define ASTRIDE 68          // 64 + 4 pad (keeps float4 alignment, breaks bank stride)
#define BSTRIDE 132         // 128 + 4 pad
#define CSTRIDE 133         // odd stride -> conflict-free row scans
#define KMAX 16

__device__ __forceinline__ float gelu_exact(float t) {
    return 0.5f * t * (1.0f + erff(t * 0.70710678118654752f));
}

// ---- Kernel S: causal score tile GEMM + per-window top-K ----------------
__global__ __launch_bounds__(NTHREADS) void score_topk_kernel(
    const float* __restrict__ h,
    float* __restrict__ pval,   // (B,T,NJC,KMAX)
    int*   __restrict__ pidx,   // (B,T,NJC,KMAX)
    int K)
{
    const int jc = blockIdx.x, it = blockIdx.y, b = blockIdx.z;
    const int i0 = it * RTILE, j0 = jc * CTILE;
    if (j0 > i0 + (RTILE - 1)) return;   // window entirely acausal

    __shared__ float smem[RTILE * CSTRIDE];   // union: {A,B staging} / C tile
    __shared__ float s_pv[RTILE][4];
    __shared__ int   s_pc[RTILE][4];

    float* Asm = smem;                     // [DCHUNK][ASTRIDE], transposed
    float* Bsm = smem + DCHUNK * ASTRIDE;  // [DCHUNK][BSTRIDE], transposed

    const int tid = threadIdx.x;
    const int tx = tid & 15, ty = tid >> 4;

    const float* hb = h + (size_t)b * TT * DD;

    float acc[4][8];
    #pragma unroll
    for (int r = 0; r < 4; ++r)
        #pragma unroll
        for (int c = 0; c < 8; ++c) acc[r][c] = 0.f;

    for (int d0 = 0; d0 < DD; d0 += DCHUNK) {
        __syncthreads();
        // stage A: 64 rows x 32 d (transposed into LDS)
        #pragma unroll
        for (int s = 0; s < 2; ++s) {
            const int q = tid + NTHREADS * s;
            const int r = q >> 3;
            const int dq = (q & 7) << 2;
            const float4 v = *(const float4*)(hb + (size_t)(i0 + r) * DD + d0 + dq);
            Asm[(dq + 0) * ASTRIDE + r] = v.x;
            Asm[(dq + 1) * ASTRIDE + r] = v.y;
            Asm[(dq + 2) * ASTRIDE + r] = v.z;
            Asm[(dq + 3) * ASTRIDE + r] = v.w;
        }
        // stage B: 128 rows x 32 d
        #pragma unroll
        for (int s = 0; s < 4; ++s) {
            const int q = tid + NTHREADS * s;
            const int r = q >> 3;
            const int dq = (q & 7) << 2;
            const float4 v = *(const float4*)(hb + (size_t)(j0 + r) * DD + d0 + dq);
            Bsm[(dq + 0) * BSTRIDE + r] = v.x;
            Bsm[(dq + 1) * BSTRIDE + r] = v.y;
            Bsm[(dq + 2) * BSTRIDE + r] = v.z;
            Bsm[(dq + 3) * BSTRIDE + r] = v.w;
        }
        __syncthreads();
        #pragma unroll
        for (int d = 0; d < DCHUNK; ++d) {
            const float4 a  = *(const float4*)&Asm[d * ASTRIDE + ty * 4];
            const float4 b0 = *(const float4*)&Bsm[d * BSTRIDE + tx * 8];
            const float4 b1 = *(const float4*)&Bsm[d * BSTRIDE + tx * 8 + 4];
            const float av[4] = {a.x, a.y, a.z, a.w};
            const float bv[8] = {b0.x, b0.y, b0.z, b0.w, b1.x, b1.y, b1.z, b1.w};
            #pragma unroll
            for (int r = 0; r < 4; ++r)
                #pragma unroll
                for (int c = 0; c < 8; ++c)
                    acc[r][c] = fmaf(av[r], bv[c], acc[r][c]);
        }
    }
    __syncthreads();

    // write causally-masked score tile into LDS (stride 133 -> conflict-free scans)
    #pragma unroll
    for (int r = 0; r < 4; ++r) {
        const int i = i0 + ty * 4 + r;
        #pragma unroll
        for (int c = 0; c < 8; ++c) {
            const int j = j0 + tx * 8 + c;
            smem[(ty * 4 + r) * CSTRIDE + tx * 8 + c] = (j <= i) ? acc[r][c] : -INFINITY;
        }
    }
    __syncthreads();

    // per-window top-K: 4 threads per row, K parallel argmax passes
    const int rloc = tid >> 2, seg = tid & 3;
    float* Crow = smem + rloc * CSTRIDE;
    for (int k = 0; k < K; ++k) {
        float best = -INFINITY; int bc = -1;
        for (int cc = 0; cc < 32; ++cc) {
            const int c = seg + (cc << 2);       // interleaved -> bank-spread
            const float v = Crow[c];
            if (v > best || (v == best && bc >= 0 && c < bc)) { best = v; bc = c; }
        }
        s_pv[rloc][seg] = best; s_pc[rloc][seg] = bc;
        __syncthreads();
        if (seg == 0) {
            float bv = s_pv[rloc][0]; int bcc = s_pc[rloc][0];
            #pragma unroll
            for (int s = 1; s < 4; ++s) {
                const float v = s_pv[rloc][s]; const int c = s_pc[rloc][s];
                if (c >= 0 && (v > bv || (v == bv && (bcc < 0 || c < bcc)))) { bv = v; bcc = c; }
            }
            const int i = i0 + rloc;
            const size_t base = ((size_t)(b * TT + i) * NJC + jc) * KMAX + k;
            pval[base] = bv;
            pidx[base] = (bcc >= 0) ? (j0 + bcc) : -1;
            if (bcc >= 0) Crow[bcc] = -INFINITY;  // remove winner
        }
        __syncthreads();
    }
}

// ---- Kernel T: merge window top-Ks, gather, epilogue --------------------
__global__ __launch_bounds__(NTHREADS) void merge_agg_kernel(
    const float* __restrict__ h_in,
    float* __restrict__ h_out,
    const float* __restrict__ pval,
    const int*   __restrict__ pidx,
    const float* __restrict__ gain,
    const float* __restrict__ bias,
    const float* __restrict__ log_mix_r,
    const float* __restrict__ log_momentum,
    int K)
{
    __shared__ float s_wv[4];
    __shared__ int   s_wj[4];
    __shared__ int   s_sel[KMAX];

    const int row = blockIdx.x, b = row / TT, i = row % TT;
    const int tid = threadIdx.x, lane = tid & 63, wave = tid >> 6;
    const float* hb = h_in + (size_t)b * TT * DD;

    const int jcn = i / CTILE + 1;
    const int ncand = jcn * K;          // <= 256
    float mv = -INFINITY; int mj = -1;
    if (tid < ncand) {
        const int w = tid / K, k = tid - w * K;
        const size_t base = ((size_t)(b * TT + i) * NJC + w) * KMAX + k;
        const int j = pidx[base];
        if (j >= 0) { mj = j; mv = pval[base]; }
    }

    const int count = (i + 1 < K) ? (i + 1) : K;
    for (int k = 0; k < count; ++k) {
        float v = mv; int j = mj;
        #pragma unroll
        for (int off = 32; off >= 1; off >>= 1) {
            const float ov = __shfl_down(v, off, 64);
            const int   oj = __shfl_down(j, off, 64);
            if (oj >= 0 && (ov > v || (ov == v && (j < 0 || oj < j)))) { v = ov; j = oj; }
        }
        if (lane == 0) { s_wv[wave] = v; s_wj[wave] = j; }
        __syncthreads();
        if (tid == 0) {
            float bv = s_wv[0]; int bj = s_wj[0];
            #pragma unroll
            for (int w = 1; w < 4; ++w) {
                const float wv = s_wv[w]; const int wj = s_wj[w];
                if (wj >= 0 && (wv > bv || (wv == bv && (bj < 0 || wj < bj)))) { bv = wv; bj = wj; }
            }
            s_sel[k] = bj;
        }
        __syncthreads();
        if (mj >= 0 && mj == s_sel[k]) { mv = -INFINITY; mj = -1; }  // zap winner
    }

    // gather mean + gated blend + affine + GELU + momentum
    const float mix      = 1.0f / (1.0f + expf(-log_mix_r[0]));
    const float momentum = 1.0f / (1.0f + expf(-log_momentum[0]));
    const float inv_cnt  = 1.0f / (float)count;

    float4 msg = make_float4(0.f, 0.f, 0.f, 0.f);
    for (int k = 0; k < count; ++k) {
        const float4 v = ((const float4*)(hb + (size_t)s_sel[k] * DD))[tid];
        msg.x += v.x; msg.y += v.y; msg.z += v.z; msg.w += v.w;
    }

    const float4 hi = ((const float4*)(hb + (size_t)i * DD))[tid];
    const float4 g4 = ((const float4*)gain)[tid];
    const float4 c4 = ((const float4*)bias)[tid];

    float4 o;
    {
        float m, t;
        m = msg.x * inv_cnt; t = (mix * hi.x + (1.f - mix) * m) * g4.x + c4.x;
        o.x = momentum * hi.x + (1.f - momentum) * gelu_exact(t);
        m = msg.y * inv_cnt; t = (mix * hi.y + (1.f - mix) * m) * g4.y + c4.y;
        o.y = momentum * hi.y + (1.f - momentum) * gelu_exact(t);
        m = msg.z * inv_cnt; t = (mix * hi.z + (1.f - mix) * m) * g4.z + c4.z;
        o.z = momentum * hi.z + (1.f - momentum) * gelu_exact(t);
        m = msg.w * inv_cnt; t = (mix * hi.w + (1.f - mix) * m) * g4.w + c4.w;
        o.w = momentum * hi.w + (1.f - momentum) * gelu_exact(t);
    }
    ((float4*)(h_out + (size_t)row * DD))[tid] = o;
}

__global__ __launch_bounds__(NTHREADS) void finalize_kernel(
    const float* __restrict__ h,
    const float* __restrict__ x,
    float* __restrict__ out,
    const float* __restrict__ log_scale)
{
    const int idx = blockIdx.x * NTHREADS + threadIdx.x;
    const float scale = log1pf(expf(log_scale[0])) + 0.01f;
    const float4 hv = ((const float4*)h)[idx];
    const float4 xv = ((const float4*)x)[idx];
    float4 o;
    o.x = (hv.x - xv.x) * scale;
    o.y = (hv.y - xv.y) * scale;
    o.z = (hv.z - xv.z) * scale;
    o.w = (hv.w - xv.w) * scale;
    ((float4*)out)[idx] = o;
}

extern "C" void kernel_launch(void* const* d_in, const int* in_sizes, int n_in,
                              void* d_out, int out_size, void* d_ws, size_t ws_size,
                              hipStream_t stream) {
    const float* x            = (const float*)d_in[0];
    const float* gain         = (const float*)d_in[1];
    const float* bias         = (const float*)d_in[2];
    const float* log_mix      = (const float*)d_in[3];
    const float* log_momentum = (const float*)d_in[4];
    const float* log_scale    = (const float*)d_in[5];
    float* out = (float*)d_out;

    // ws layout: h buffer (16.78 MB) | pval (4.19 MB) | pidx (4.19 MB)
    float* h_ws = (float*)d_ws;
    float* pval = (float*)((char*)d_ws + (size_t)BB * TT * DD * 4);
    int*   pidx = (int*)((char*)pval + (size_t)BB * TT * NJC * KMAX * 4);

    const dim3 sgrid(NJC, NIT, BB);

    // round 0: x -> h_ws
    score_topk_kernel<<<sgrid, NTHREADS, 0, stream>>>(x, pval, pidx, 4);
    merge_agg_kernel<<<BB * TT, NTHREADS, 0, stream>>>(
        x, h_ws, pval, pidx, gain + 0 * DD, bias + 0 * DD, log_mix + 0, log_momentum, 4);
    // round 1: h_ws -> d_out
    score_topk_kernel<<<sgrid, NTHREADS, 0, stream>>>(h_ws, pval, pidx, 8);
    merge_agg_kernel<<<BB * TT, NTHREADS, 0, stream>>>(
        h_ws, out, pval, pidx, gain + 1 * DD, bias + 1 * DD, log_mix + 1, log_momentum, 8);
    // round 2: d_out -> h_ws
    score_topk_kernel<<<sgrid, NTHREADS, 0, stream>>>(out, pval, pidx, 16);
    merge_agg_kernel<<<BB * TT, NTHREADS, 0, stream>>>(
        out, h_ws, pval, pidx, gain + 2 * DD, bias + 2 * DD, log_mix + 2, log_momentum, 16);
    // finalize: (h_ws, x) -> out
    const int n4 = BB * TT * DD / 4;
    finalize_kernel<<<n4 / NTHREADS, NTHREADS, 0, stream>>>(h_ws, x, out, log_scale);
}

// Round 3
// 731.254 us; speedup vs baseline: 2.9263x; 1.1899x over previous
//
#include <hip/hip_runtime.h>
#include <math.h>

#define BB 2
#define TT 2048
#define DD 1024
#define NTHREADS 256

#define RT 32               // rows per score tile
#define CT 128              // cols per score tile (= top-K window width)
#define DC 32               // d-chunk
#define NJC (TT / CT)       // 16 windows per row
#define KMAX 16
#define CST 132             // C-tile stride: 4 mod 32 -> 2-way (free) scans
#define NTILES 544          // causal tiles per batch: sum_{it<64}(it/4+1)

__device__ __forceinline__ float gelu_exact(float t) {
    return 0.5f * t * (1.0f + erff(t * 0.70710678118654752f));
}

// ---- Kernel S: causal 32x128 score tile (fp32 FMA) + per-window top-K ----
__global__ __launch_bounds__(NTHREADS) void score_topk_kernel(
    const float* __restrict__ h,
    float* __restrict__ pval,   // (B,T,NJC,KMAX)
    int*   __restrict__ pidx,   // (B,T,NJC,KMAX)
    int K)
{
    // smem union: staging {Asm[32][32] | Bsm[32][128]} (5120 f) / C tile 32x132 (4224 f)
    __shared__ __align__(16) float smem[5120];
    __shared__ float s_pv[RT][8];
    __shared__ int   s_pc[RT][8];

    // triangular grid decode: p -> (it, jc), it in [0,64), jc in [0, it/4]
    const int b = blockIdx.y;
    const int p = blockIdx.x;
    int g = (int)(0.5f * (sqrtf(2.0f * (float)p + 1.0f) - 1.0f));
    while (2 * (g + 1) * (g + 2) <= p) ++g;
    while (2 * g * (g + 1) > p) --g;
    const int qq = p - 2 * g * (g + 1);
    const int it = 4 * g + qq / (g + 1);
    const int jc = qq % (g + 1);
    const int i0 = it * RT, j0 = jc * CT;

    const int tid = threadIdx.x;
    const int tx = tid & 31;        // col group (4 cols)
    const int ty = tid >> 5;        // row group (4 rows), 0..7
    const float* hb = h + (size_t)b * TT * DD;

    float* Asm = smem;              // [d][32], xor-swizzled
    float* Bsm = smem + RT * DC;    // [d][128], xor-swizzled

    // staging geometry (per thread): one A float4 + four B float4 per chunk
    const int ra  = tid >> 3;           // 0..31: A row / B row base
    const int da  = (tid & 7) << 2;     // 0..28: d offset of the float4
    const int swa = tid & 7;            // (d'>>2)&7 for all 4 dwords
    const int posA = (ra & 3) + 4 * ((ra >> 2) ^ swa);
    int posB[4];
    #pragma unroll
    for (int s = 0; s < 4; ++s) {
        const int c = 32 * s + ra;      // 0..127
        posB[s] = (c & 3) + 4 * (((c >> 2) ^ swa) & 31);
    }
    const float* aptr = hb + (size_t)(i0 + ra) * DD + da;
    const float* bptr0 = hb + (size_t)(j0 + ra +  0) * DD + da;
    const float* bptr1 = hb + (size_t)(j0 + ra + 32) * DD + da;
    const float* bptr2 = hb + (size_t)(j0 + ra + 64) * DD + da;
    const float* bptr3 = hb + (size_t)(j0 + ra + 96) * DD + da;

    float acc[4][4] = {{0.f}};

    // prefetch chunk 0
    float4 va  = *(const float4*)(aptr);
    float4 vb0 = *(const float4*)(bptr0);
    float4 vb1 = *(const float4*)(bptr1);
    float4 vb2 = *(const float4*)(bptr2);
    float4 vb3 = *(const float4*)(bptr3);

    for (int d0 = 0; d0 < DD; d0 += DC) {
        __syncthreads();
        {
            const float av[4] = {va.x, va.y, va.z, va.w};
            const float b0[4] = {vb0.x, vb0.y, vb0.z, vb0.w};
            const float b1[4] = {vb1.x, vb1.y, vb1.z, vb1.w};
            const float b2[4] = {vb2.x, vb2.y, vb2.z, vb2.w};
            const float b3[4] = {vb3.x, vb3.y, vb3.z, vb3.w};
            #pragma unroll
            for (int t = 0; t < 4; ++t) {
                Asm[(da + t) * RT + posA]    = av[t];
                Bsm[(da + t) * CT + posB[0]] = b0[t];
                Bsm[(da + t) * CT + posB[1]] = b1[t];
                Bsm[(da + t) * CT + posB[2]] = b2[t];
                Bsm[(da + t) * CT + posB[3]] = b3[t];
            }
        }
        __syncthreads();

        // prefetch next chunk while computing this one
        if (d0 + DC < DD) {
            const int nd = d0 + DC;
            va  = *(const float4*)(aptr + nd);
            vb0 = *(const float4*)(bptr0 + nd);
            vb1 = *(const float4*)(bptr1 + nd);
            vb2 = *(const float4*)(bptr2 + nd);
            vb3 = *(const float4*)(bptr3 + nd);
        }

        #pragma unroll
        for (int d = 0; d < DC; ++d) {
            const int sw = (d >> 2) & 7;
            const float4 af = *(const float4*)&Asm[d * RT + 4 * (ty ^ sw)];
            const float4 bf = *(const float4*)&Bsm[d * CT + 4 * (tx ^ sw)];
            const float aa[4] = {af.x, af.y, af.z, af.w};
            const float bb[4] = {bf.x, bf.y, bf.z, bf.w};
            #pragma unroll
            for (int r = 0; r < 4; ++r)
                #pragma unroll
                for (int c = 0; c < 4; ++c)
                    acc[r][c] = fmaf(aa[r], bb[c], acc[r][c]);
        }
    }
    __syncthreads();

    // causally-masked C tile into LDS
    #pragma unroll
    for (int r = 0; r < 4; ++r) {
        const int i = i0 + ty * 4 + r;
        #pragma unroll
        for (int c = 0; c < 4; ++c) {
            const int j = j0 + tx * 4 + c;
            smem[(ty * 4 + r) * CST + tx * 4 + c] = (j <= i) ? acc[r][c] : -INFINITY;
        }
    }
    __syncthreads();

    // per-window top-K: 8 threads/row, K argmax passes
    const int rloc = tid >> 3, seg = tid & 7;
    float* Crow = smem + rloc * CST;
    const int irow = i0 + rloc;
    for (int k = 0; k < K; ++k) {
        float best = -INFINITY; int bc = -1;
        #pragma unroll
        for (int cc = 0; cc < 16; ++cc) {
            const int c = seg + (cc << 3);
            const float v = Crow[c];
            if (v > best) { best = v; bc = c; }
        }
        s_pv[rloc][seg] = best; s_pc[rloc][seg] = bc;
        __syncthreads();
        if (seg == 0) {
            float bv = best; int bcc = bc;
            #pragma unroll
            for (int s2 = 1; s2 < 8; ++s2) {
                const float v = s_pv[rloc][s2]; const int c2 = s_pc[rloc][s2];
                if (c2 >= 0 && (v > bv || (v == bv && (bcc < 0 || c2 < bcc)))) { bv = v; bcc = c2; }
            }
            const size_t base = ((size_t)(b * TT + irow) * NJC + jc) * KMAX + k;
            pval[base] = bv;
            pidx[base] = (bcc >= 0) ? (j0 + bcc) : -1;
            if (bcc >= 0) Crow[bcc] = -INFINITY;
        }
        __syncthreads();
    }
}

// ---- Kernel T: merge window top-Ks, gather, epilogue (optional fused final) ----
__global__ __launch_bounds__(NTHREADS) void merge_agg_kernel(
    const float* __restrict__ h_in,
    float* __restrict__ h_out,
    const float* __restrict__ pval,
    const int*   __restrict__ pidx,
    const float* __restrict__ gain,
    const float* __restrict__ bias,
    const float* __restrict__ log_mix_r,
    const float* __restrict__ log_momentum,
    int K,
    const float* __restrict__ xres,       // non-null => fused (h-x)*scale
    const float* __restrict__ log_scale)
{
    __shared__ float s_wv[4];
    __shared__ int   s_wj[4];
    __shared__ int   s_sel[KMAX];

    const int row = blockIdx.x, b = row / TT, i = row % TT;
    const int tid = threadIdx.x, lane = tid & 63, wave = tid >> 6;
    const float* hb = h_in + (size_t)b * TT * DD;

    const int jcn = i / CT + 1;
    const int ncand = jcn * K;          // <= 256
    float mv = -INFINITY; int mj = -1;
    if (tid < ncand) {
        const int w = tid / K, k = tid - w * K;
        const size_t base = ((size_t)(b * TT + i) * NJC + w) * KMAX + k;
        const int j = pidx[base];
        if (j >= 0) { mj = j; mv = pval[base]; }
    }

    const int count = (i + 1 < K) ? (i + 1) : K;
    for (int k = 0; k < count; ++k) {
        float v = mv; int j = mj;
        #pragma unroll
        for (int off = 32; off >= 1; off >>= 1) {
            const float ov = __shfl_down(v, off, 64);
            const int   oj = __shfl_down(j, off, 64);
            if (oj >= 0 && (ov > v || (ov == v && (j < 0 || oj < j)))) { v = ov; j = oj; }
        }
        if (lane == 0) { s_wv[wave] = v; s_wj[wave] = j; }
        __syncthreads();
        if (tid == 0) {
            float bv = s_wv[0]; int bj = s_wj[0];
            #pragma unroll
            for (int w = 1; w < 4; ++w) {
                const float wv = s_wv[w]; const int wj = s_wj[w];
                if (wj >= 0 && (wv > bv || (wv == bv && (bj < 0 || wj < bj)))) { bv = wv; bj = wj; }
            }
            s_sel[k] = bj;
        }
        __syncthreads();
        if (mj >= 0 && mj == s_sel[k]) { mv = -INFINITY; mj = -1; }
    }

    const float mix      = 1.0f / (1.0f + expf(-log_mix_r[0]));
    const float momentum = 1.0f / (1.0f + expf(-log_momentum[0]));
    const float inv_cnt  = 1.0f / (float)count;

    float4 msg = make_float4(0.f, 0.f, 0.f, 0.f);
    for (int k = 0; k < count; ++k) {
        const float4 v = ((const float4*)(hb + (size_t)s_sel[k] * DD))[tid];
        msg.x += v.x; msg.y += v.y; msg.z += v.z; msg.w += v.w;
    }

    const float4 hi = ((const float4*)(hb + (size_t)i * DD))[tid];
    const float4 g4 = ((const float4*)gain)[tid];
    const float4 c4 = ((const float4*)bias)[tid];

    float4 o;
    {
        float m, t;
        m = msg.x * inv_cnt; t = (mix * hi.x + (1.f - mix) * m) * g4.x + c4.x;
        o.x = momentum * hi.x + (1.f - momentum) * gelu_exact(t);
        m = msg.y * inv_cnt; t = (mix * hi.y + (1.f - mix) * m) * g4.y + c4.y;
        o.y = momentum * hi.y + (1.f - momentum) * gelu_exact(t);
        m = msg.z * inv_cnt; t = (mix * hi.z + (1.f - mix) * m) * g4.z + c4.z;
        o.z = momentum * hi.z + (1.f - momentum) * gelu_exact(t);
        m = msg.w * inv_cnt; t = (mix * hi.w + (1.f - mix) * m) * g4.w + c4.w;
        o.w = momentum * hi.w + (1.f - momentum) * gelu_exact(t);
    }

    if (xres != nullptr) {
        const float scale = log1pf(expf(log_scale[0])) + 0.01f;
        const float4 xv = ((const float4*)(xres + (size_t)row * DD))[tid];
        o.x = (o.x - xv.x) * scale;
        o.y = (o.y - xv.y) * scale;
        o.z = (o.z - xv.z) * scale;
        o.w = (o.w - xv.w) * scale;
    }
    ((float4*)(h_out + (size_t)row * DD))[tid] = o;
}

extern "C" void kernel_launch(void* const* d_in, const int* in_sizes, int n_in,
                              void* d_out, int out_size, void* d_ws, size_t ws_size,
                              hipStream_t stream) {
    const float* x            = (const float*)d_in[0];
    const float* gain         = (const float*)d_in[1];
    const float* bias         = (const float*)d_in[2];
    const float* log_mix      = (const float*)d_in[3];
    const float* log_momentum = (const float*)d_in[4];
    const float* log_scale    = (const float*)d_in[5];
    float* out = (float*)d_out;

    // ws: h buffer (16.78 MB) | pval (4.19 MB) | pidx (4.19 MB)
    float* h_ws = (float*)d_ws;
    float* pval = (float*)((char*)d_ws + (size_t)BB * TT * DD * 4);
    int*   pidx = (int*)((char*)pval + (size_t)BB * TT * NJC * KMAX * 4);

    const dim3 sgrid(NTILES, BB);

    // buffer rotation: x -> out -> h_ws -> out(final, fused)
    score_topk_kernel<<<sgrid, NTHREADS, 0, stream>>>(x, pval, pidx, 4);
    merge_agg_kernel<<<BB * TT, NTHREADS, 0, stream>>>(
        x, out, pval, pidx, gain + 0 * DD, bias + 0 * DD, log_mix + 0, log_momentum, 4,
        nullptr, nullptr);
    score_topk_kernel<<<sgrid, NTHREADS, 0, stream>>>(out, pval, pidx, 8);
    merge_agg_kernel<<<BB * TT, NTHREADS, 0, stream>>>(
        out, h_ws, pval, pidx, gain + 1 * DD, bias + 1 * DD, log_mix + 1, log_momentum, 8,
        nullptr, nullptr);
    score_topk_kernel<<<sgrid, NTHREADS, 0, stream>>>(h_ws, pval, pidx, 16);
    merge_agg_kernel<<<BB * TT, NTHREADS, 0, stream>>>(
        h_ws, out, pval, pidx, gain + 2 * DD, bias + 2 * DD, log_mix + 2, log_momentum, 16,
        x, log_scale);
}